// Round 6
// baseline (599.587 us; speedup 1.0000x reference)
//
#include <hip/hip_runtime.h>
#include <stdint.h>

// BaseOpenSetClassifier: per-pixel sq-euclid distance to K templates + min/argmin.
// B=16, N=16384, D=64, K=64, thresholds {0.5, 1.0}.
//
// R13 = SGEMM-style 4x4 register tiles + wave-private dbuf pipeline, 0 barriers.
// EVIDENCE (R10-R12): 145-165us plateau, HBM 10-13%, VALU 20-25%, occ 20%,
// conflicts ~0 -- no visible pipe busy. R12's stage/compute overlap was NULL
// => stage wasn't the cost. Remaining suspect: LDS return bus. lane=k reads
// xv as wave-UNIFORM ds_read_b128: bus ships 1024B for 16 useful B, 256
// reads/pixel = ~256KB/pixel through 128B/cyc => ~68us/CU hidden serialization.
// Changes:
//  - Register tiling: lane=(bg=lane>>4, kg=lane&15) owns 4b x 4k cells. Per
//    d-quad: 4 x-reads + 4 t-reads (lane-DISTINCT addrs) feed 16 cells x 4 pk
//    => 128 reads / ~128KB bus per pixel (2x fewer instrs AND bytes than R11;
//    win under either LDS cost model).
//  - XOR swizzle slot = dq ^ (row>>2): t-reads hit 8 bank-quads x 2 lanes
//    (2-way = free, m136); x-reads 4 distinct quads + broadcast dups. Source
//    pre-swizzled for linear gll dest (rule 21, same involution both sides).
//  - Wave-private pipeline: WG = 1 wave (64 thr), 2x20KB LDS dbuf, 16 px/wave,
//    ZERO __syncthreads. Prefetch px i+1 via gll under compute(i); handoff =
//    per-wave s_waitcnt vmcnt(0) (+sched_barrier, rule 18). 4 waves/CU
//    (160KB), free-running skew; aggregate prefetch 26 B/cyc > 10.25 HBM share
//    => HBM saturated by construction. i-loop steps 2 px with sb0/sb1 constant
//    so gll(sbA) vs ds_read(sbB) are alias-provably distinct (no spurious
//    compiler vmcnt waits).
//  - Numerics BIT-EXACT R8 (absmax-0.0 provenance): same d-pairing (d0=pairs
//    4dq,4dq+1; d1=4dq+2,4dq+3), fresh a0/a1 chains per half, acc+=a0+a1,
//    dme=acc.x+acc.y; strict-< ascending k in-lane + lex-min shfl butterfly
//    => first-index ties == jnp.argmin.
// Budget: HBM 51us (binding) > LDS 27us > VALU ~20us/SIMD => BW-bound design.

#define BB 16
#define NN 16384
#define DD 64
#define KK 64
#define PPW 16   // pixels per wave

typedef float v2f __attribute__((ext_vector_type(2)));

__device__ __forceinline__ void gll16(const void* g, void* l) {
    // global_load_lds_dwordx4: per-lane global src, wave-uniform LDS base,
    // HW writes base + lane*16 (linear).
    __builtin_amdgcn_global_load_lds(
        (const __attribute__((address_space(1))) void*)g,
        (__attribute__((address_space(3))) void*)l, 16, 0, 0);
}

__global__ __launch_bounds__(64, 1)
void openset_kernel(const float* __restrict__ x,     // [B,N,D]
                    const float* __restrict__ tmpl,  // [K,N,D]
                    const int*   __restrict__ tcls,  // [K]
                    float*       __restrict__ out) { // [2*B*N | B*N | B*N]
    // Two 20KB halves: [ t: 1024 f4 (64 k-rows x 16 quads, XOR-swizzled)
    //                  | x:  256 f4 (16 b-rows x 16 quads, XOR-swizzled) ]
    __shared__ float4 sb0[1280];
    __shared__ float4 sb1[1280];

    const int lane = threadIdx.x;        // block = 1 wave
    const int kg   = lane & 15;          // k-group: lane's k = 4kg..4kg+3
    const int bg   = lane >> 4;          // b-group: lane's b = 4bg..4bg+3
    const int rs   = lane >> 4;          // staging: row within a 4-row group
    const int s    = lane & 15;          // staging: dest slot (f4 within row)

    // XCD swizzle: XCD i (= blk&7) owns pixels [i*2048,(i+1)*2048); 16/wave.
    const int pbase = (int)(((blockIdx.x & 7) << 11) | ((blockIdx.x >> 3) << 4));

    // ---- Stage pixel p into dst: 16 t-gll + 4 x-gll, each 1024B covering 4
    // rows. Dest linear (rule 21); source quad pre-swizzled s^c so the read
    // side's (dq ^ row>>2) lands on the right data (row>>2 == c for all 4
    // rows of gll c).
    auto stage = [&](int p, float4* dst) {
#pragma unroll
        for (int c = 0; c < 16; ++c) {
            const int k = 4 * c + rs;
            const float4* src =
                (const float4*)(tmpl + ((size_t)k << 20) + (size_t)p * DD)
                + (s ^ c);
            gll16(src, dst + c * 64);
        }
#pragma unroll
        for (int c = 0; c < 4; ++c) {
            const int b = 4 * c + rs;
            const float4* src =
                (const float4*)(x + ((size_t)b << 20) + (size_t)p * DD)
                + (s ^ c);
            gll16(src, dst + 1024 + c * 64);
        }
    };

    // ---- Compute pixel p from buf: 4b x 4k cells, R8-exact accumulation.
    auto compute = [&](const float4* buf, int p) {
        v2f acc[4][4];
#pragma unroll
        for (int b2 = 0; b2 < 4; ++b2)
#pragma unroll
            for (int t2 = 0; t2 < 4; ++t2) acc[b2][t2] = (v2f){0.f, 0.f};

#pragma unroll
        for (int h = 0; h < 2; ++h) {
            v2f a0[4][4], a1[4][4];
#pragma unroll
            for (int b2 = 0; b2 < 4; ++b2)
#pragma unroll
                for (int t2 = 0; t2 < 4; ++t2) {
                    a0[b2][t2] = (v2f){0.f, 0.f};
                    a1[b2][t2] = (v2f){0.f, 0.f};
                }
#pragma unroll
            for (int j = 0; j < 8; ++j) {
                const int dq = 8 * h + j;   // d-quad = floats 4dq..4dq+3
                float4 tv[4], xv[4];
#pragma unroll
                for (int t2 = 0; t2 < 4; ++t2)
                    tv[t2] = buf[kg * 64 + t2 * 16 + (dq ^ kg)];
#pragma unroll
                for (int b2 = 0; b2 < 4; ++b2)
                    xv[b2] = buf[1024 + bg * 64 + b2 * 16 + (dq ^ bg)];
#pragma unroll
                for (int b2 = 0; b2 < 4; ++b2)
#pragma unroll
                    for (int t2 = 0; t2 < 4; ++t2) {
                        v2f d0 = (v2f){xv[b2].x - tv[t2].x,
                                       xv[b2].y - tv[t2].y};
                        v2f d1 = (v2f){xv[b2].z - tv[t2].z,
                                       xv[b2].w - tv[t2].w};
                        a0[b2][t2] += d0 * d0;   // pk_fma chains (R8 order)
                        a1[b2][t2] += d1 * d1;
                    }
            }
#pragma unroll
            for (int b2 = 0; b2 < 4; ++b2)
#pragma unroll
                for (int t2 = 0; t2 < 4; ++t2)
                    acc[b2][t2] += a0[b2][t2] + a1[b2][t2];
        }

        // Epilogue: per bb, in-lane min over tk (ascending, strict < ->
        // smallest k on ties) then 4-step lex-min butterfly over kg lanes.
        float wd = 0.f; int wk = 0;
#pragma unroll
        for (int b2 = 0; b2 < 4; ++b2) {
            float bd = acc[b2][0].x + acc[b2][0].y;
            int   bk = 4 * kg;
#pragma unroll
            for (int t2 = 1; t2 < 4; ++t2) {
                const float dv = acc[b2][t2].x + acc[b2][t2].y;
                if (dv < bd) { bd = dv; bk = 4 * kg + t2; }
            }
#pragma unroll
            for (int m = 1; m < 16; m <<= 1) {
                const float od = __shfl_xor(bd, m);
                const int   ok = __shfl_xor(bk, m);
                if (od < bd || (od == bd && ok < bk)) { bd = od; bk = ok; }
            }
            if (kg == b2) { wd = bd; wk = bk; }   // lane kg writes b=4bg+kg
        }
        if (kg < 4) {
            const int b = 4 * bg + kg;
            const size_t BN = (size_t)BB * NN;
            const size_t o  = (size_t)b * NN + p;
            out[o]          = (wd <= 0.5f) ? 1.0f : 0.0f;  // masks[0] @0.5
            out[BN + o]     = (wd <= 1.0f) ? 1.0f : 0.0f;  // masks[1] @1.0
            out[2 * BN + o] = wd;                          // min_dists
            out[3 * BN + o] = (float)tcls[wk];             // pred_classes
        }
    };

    // ---- Wave-private pipeline: prefetch depth 1, zero barriers.
    stage(pbase, sb0);
#pragma unroll 1
    for (int i = 0; i < PPW; i += 2) {
        asm volatile("s_waitcnt vmcnt(0)" ::: "memory");  // tile i resident
        __builtin_amdgcn_sched_barrier(0);                // rule 18 fence
        if (i + 1 < PPW) stage(pbase + i + 1, sb1);       // fly under compute
        compute(sb0, pbase + i);

        asm volatile("s_waitcnt vmcnt(0)" ::: "memory");  // tile i+1 resident
        __builtin_amdgcn_sched_barrier(0);
        if (i + 2 < PPW) stage(pbase + i + 2, sb0);
        compute(sb1, pbase + i + 1);
    }
}

extern "C" void kernel_launch(void* const* d_in, const int* in_sizes, int n_in,
                              void* d_out, int out_size, void* d_ws, size_t ws_size,
                              hipStream_t stream) {
    const float* x    = (const float*)d_in[0];   // frame_embeddings [16,16384,64]
    const float* tmpl = (const float*)d_in[1];   // templates       [64,16384,64]
    const int*   tcls = (const int*)d_in[2];     // template_classes [64]
    float* out = (float*)d_out;

    dim3 grid(NN / PPW);  // 1024 single-wave blocks; 4/CU = full 160KB LDS
    dim3 block(64);
    openset_kernel<<<grid, block, 0, stream>>>(x, tmpl, tcls, out);
}